// Round 2
// baseline (31772.940 us; speedup 1.0000x reference)
//
#include <hip/hip_runtime.h>
#include <hip/hip_fp16.h>
#include <math.h>

#define B 64
#define L 128
#define N_ 512
#define E_ 512
#define H_ 512
#define NEG -1e9f

// ---------------- precompute kernels (run once per call) ----------------

__global__ __launch_bounds__(256) void k_init(const float* __restrict__ state,
                                              float* __restrict__ hb,
                                              float* __restrict__ cov) {
  int i = blockIdx.x * 256 + threadIdx.x;
  if (i < B * H_) hb[i] = state[i];
  if (i < B * N_) cov[i] = 0.f;
}

// fp32 -> fp16 copy of value (context path)
__global__ __launch_bounds__(256) void k_cvt(const float* __restrict__ v,
                                             __half* __restrict__ o) {
  size_t i = ((size_t)blockIdx.x * 256 + threadIdx.x) * 4;
  float4 f = *(const float4*)(v + i);
  __half2* d = (__half2*)(o + i);
  d[0] = __floats2half2_rn(f.x, f.y);
  d[1] = __floats2half2_rn(f.z, f.w);
}

// vk[b,n,k] = sum_h value[b,n,h] * Wk[k,h] + b_attn[k]   (stored fp16)
__global__ __launch_bounds__(256) void k_vk(const float* __restrict__ value,
                                            const float* __restrict__ Wk,
                                            const float* __restrict__ b_attn,
                                            __half* __restrict__ vk) {
  int k0 = blockIdx.x * 64, n0 = blockIdx.y * 64, b = blockIdx.z;
  int tid = threadIdx.x;
  int tn = tid >> 4, tk = tid & 15;
  __shared__ float Vs[64][33];
  __shared__ float Ws[64][33];
  const float* vb = value + (size_t)b * N_ * H_;
  float acc[4][4] = {};
  for (int h0 = 0; h0 < H_; h0 += 32) {
#pragma unroll
    for (int e = 0; e < 8; ++e) {
      int idx = tid + e * 256;
      int r = idx >> 5, c = idx & 31;
      Vs[r][c] = vb[(size_t)(n0 + r) * H_ + h0 + c];
      Ws[r][c] = Wk[(size_t)(k0 + r) * H_ + h0 + c];
    }
    __syncthreads();
#pragma unroll
    for (int c = 0; c < 32; ++c) {
      float av[4], wv[4];
#pragma unroll
      for (int i = 0; i < 4; ++i) av[i] = Vs[tn * 4 + i][c];
#pragma unroll
      for (int jq = 0; jq < 4; ++jq) wv[jq] = Ws[tk * 4 + jq][c];
#pragma unroll
      for (int i = 0; i < 4; ++i)
#pragma unroll
        for (int jq = 0; jq < 4; ++jq) acc[i][jq] += av[i] * wv[jq];
    }
    __syncthreads();
  }
  __half* vkb = vk + (size_t)b * N_ * H_;
  float4 bav = *(const float4*)(b_attn + k0 + tk * 4);
#pragma unroll
  for (int i = 0; i < 4; ++i) {
    __half2 lo = __floats2half2_rn(acc[i][0] + bav.x, acc[i][1] + bav.y);
    __half2 hi = __floats2half2_rn(acc[i][2] + bav.z, acc[i][3] + bav.w);
    __half2* dst = (__half2*)&vkb[(size_t)(n0 + tn * 4 + i) * H_ + k0 + tk * 4];
    dst[0] = lo;
    dst[1] = hi;
  }
}

// ---------------- per-step: q = h @ Wq.T ----------------
// 128 WGs x 4 waves; wave owns output row j (Wq row via wave-uniform loads),
// lanes = batches, h staged in LDS.
__global__ __launch_bounds__(256) void k_q(const float* __restrict__ h_in,
                                           const float* __restrict__ Wq,
                                           float* __restrict__ q) {
  int tid = threadIdx.x;
  int b = tid & 63;
  int w = tid >> 6;
  int j = __builtin_amdgcn_readfirstlane(blockIdx.x * 4 + w);
  __shared__ float xt[64][65];
  const float* wr = Wq + (size_t)j * H_;
  float acc = 0.f;
  for (int c0 = 0; c0 < H_; c0 += 64) {
    __syncthreads();
#pragma unroll
    for (int e = 0; e < 16; ++e) {
      int idx = tid + e * 256;
      int r = idx >> 6, c = idx & 63;
      xt[r][c] = h_in[r * H_ + c0 + c];
    }
    __syncthreads();
#pragma unroll
    for (int c = 0; c < 64; ++c) acc = fmaf(xt[b][c], wr[c0 + c], acc);
  }
  q[b * H_ + j] = acc;
}

// ---------------- per-step: masked scores ----------------
// grid (4, B): WG computes 128 score rows for one batch.
// lane l owns h in [8l, 8l+8): one 16B fp16 load per row.
__global__ __launch_bounds__(256) void k_score(
    const __half* __restrict__ vk, const float* __restrict__ q,
    const float* __restrict__ w_cov, const float* __restrict__ v_attn,
    const float* __restrict__ cov, const float* __restrict__ vmask,
    float* __restrict__ scores) {
  int b = blockIdx.y, n0 = blockIdx.x * 128;
  int tid = threadIdx.x, w = tid >> 6, l = tid & 63;
  __shared__ float qs[H_];
  __shared__ float covs[128];
  __shared__ float sc[128];
  qs[tid] = q[b * H_ + tid];
  qs[tid + 256] = q[b * H_ + tid + 256];
  if (tid < 128) covs[tid] = cov[b * N_ + n0 + tid];
  __syncthreads();

  float q8[8], wc8[8], va8[8];
  {
    float4 a0 = *(const float4*)(w_cov + l * 8);
    float4 a1 = *(const float4*)(w_cov + l * 8 + 4);
    wc8[0] = a0.x; wc8[1] = a0.y; wc8[2] = a0.z; wc8[3] = a0.w;
    wc8[4] = a1.x; wc8[5] = a1.y; wc8[6] = a1.z; wc8[7] = a1.w;
    float4 b0 = *(const float4*)(v_attn + l * 8);
    float4 b1 = *(const float4*)(v_attn + l * 8 + 4);
    va8[0] = b0.x; va8[1] = b0.y; va8[2] = b0.z; va8[3] = b0.w;
    va8[4] = b1.x; va8[5] = b1.y; va8[6] = b1.z; va8[7] = b1.w;
  }
#pragma unroll
  for (int k = 0; k < 8; ++k) q8[k] = qs[l * 8 + k];

  const __half* vkb = vk + ((size_t)b * N_ + n0) * H_;
  for (int r = 0; r < 32; ++r) {
    int n = w * 32 + r;
    float cv = covs[n];
    float qc[8];
#pragma unroll
    for (int k = 0; k < 8; ++k) qc[k] = fmaf(cv, wc8[k], q8[k]);
    float4 raw = *(const float4*)(vkb + (size_t)n * H_ + l * 8);
    const __half2* hp2 = (const __half2*)&raw;
    float p = 0.f;
#pragma unroll
    for (int k = 0; k < 4; ++k) {
      float2 f = __half22float2(hp2[k]);
      p = fmaf(fmaxf(qc[2 * k] + f.x, 0.f), va8[2 * k], p);
      p = fmaf(fmaxf(qc[2 * k + 1] + f.y, 0.f), va8[2 * k + 1], p);
    }
#pragma unroll
    for (int off = 32; off; off >>= 1) p += __shfl_xor(p, off);
    if (l == 0) sc[n] = p;
  }
  __syncthreads();
  if (tid < 128) {
    int n = n0 + tid;
    scores[b * N_ + n] = (vmask[b * N_ + n] > 0.f) ? sc[tid] : NEG;
  }
}

// ---------------- per-step: softmax + context + cov ----------------
// grid (4, B): WG = one h-quarter of one batch; softmax recomputed per WG.
__global__ __launch_bounds__(256) void k_ctx(
    const float* __restrict__ scores, const __half* __restrict__ val_h,
    float* __restrict__ cov, float* __restrict__ ctx,
    float* __restrict__ attn_out, int t) {
  int b = blockIdx.y, h0 = blockIdx.x * 128;
  int tid = threadIdx.x;
  __shared__ float at[N_];
  __shared__ float red[256];
  __shared__ float2 redc[4][64];

  float s0 = scores[b * N_ + tid], s1 = scores[b * N_ + tid + 256];
  red[tid] = fmaxf(s0, s1);
  __syncthreads();
#pragma unroll
  for (int s = 128; s; s >>= 1) {
    if (tid < s) red[tid] = fmaxf(red[tid], red[tid + s]);
    __syncthreads();
  }
  float m = red[0];
  __syncthreads();
  float p0 = expf(s0 - m), p1 = expf(s1 - m);
  red[tid] = p0 + p1;
  __syncthreads();
#pragma unroll
  for (int s = 128; s; s >>= 1) {
    if (tid < s) red[tid] += red[tid + s];
    __syncthreads();
  }
  float rinv = 1.f / red[0];
  float a0 = p0 * rinv, a1 = p1 * rinv;
  at[tid] = a0;
  at[tid + 256] = a1;
  if (blockIdx.x == 0) {
    attn_out[((size_t)b * L + t) * N_ + tid] = a0;
    attn_out[((size_t)b * L + t) * N_ + tid + 256] = a1;
    cov[b * N_ + tid] += a0;
    cov[b * N_ + tid + 256] += a1;
  }
  __syncthreads();

  int w = tid >> 6, l = tid & 63;
  float2 acc = make_float2(0.f, 0.f);
  const __half2* vb = (const __half2*)(val_h + (size_t)b * N_ * H_ + h0) + l;
  for (int n = w; n < N_; n += 4) {
    float a = at[n];
    float2 f = __half22float2(vb[(size_t)n * (H_ / 2)]);
    acc.x = fmaf(a, f.x, acc.x);
    acc.y = fmaf(a, f.y, acc.y);
  }
  redc[w][l] = acc;
  __syncthreads();
  if (w == 0) {
#pragma unroll
    for (int k = 1; k < 4; ++k) {
      float2 o = redc[k][l];
      acc.x += o.x;
      acc.y += o.y;
    }
    ctx[b * H_ + h0 + 2 * l] = acc.x;
    ctx[b * H_ + h0 + 2 * l + 1] = acc.y;
  }
}

// ---------------- per-step: GRU ----------------
// 128 WGs, each owns 4 output rows j for all 64 batches; weights read once
// per step across the grid, wave-uniform rows (scalar loads).
__global__ __launch_bounds__(256) void k_gru(
    const float* __restrict__ emb, const float* __restrict__ ctx,
    const float* __restrict__ W_ih, const float* __restrict__ W_hh,
    const float* __restrict__ b_ih, const float* __restrict__ b_hh,
    const float* __restrict__ h_in, float* __restrict__ h_out,
    float* __restrict__ out_h, int t) {
  int tid = threadIdx.x;
  int b = tid & 63;
  int jj = tid >> 6;
  int j = __builtin_amdgcn_readfirstlane(blockIdx.x * 4 + jj);
  __shared__ float xt[64][65];

  float ar = b_ih[j], az = b_ih[j + H_], an = b_ih[j + 2 * H_];
  const float* wr = W_ih + (size_t)j * (E_ + H_);
  const float* wz = W_ih + (size_t)(j + H_) * (E_ + H_);
  const float* wn = W_ih + (size_t)(j + 2 * H_) * (E_ + H_);
  for (int i0 = 0; i0 < E_ + H_; i0 += 64) {
    __syncthreads();
#pragma unroll
    for (int e = 0; e < 16; ++e) {
      int idx = tid + e * 256;
      int r = idx >> 6, c = idx & 63;
      int i = i0 + c;
      xt[r][c] = (i < E_) ? emb[((size_t)r * L + t) * E_ + i]
                          : ctx[r * H_ + (i - E_)];
    }
    __syncthreads();
#pragma unroll
    for (int c = 0; c < 64; ++c) {
      float x = xt[b][c];
      ar = fmaf(x, wr[i0 + c], ar);
      az = fmaf(x, wz[i0 + c], az);
      an = fmaf(x, wn[i0 + c], an);
    }
  }

  float gr = b_hh[j], gz = b_hh[j + H_], gn = b_hh[j + 2 * H_];
  const float* ur = W_hh + (size_t)j * H_;
  const float* uz = W_hh + (size_t)(j + H_) * H_;
  const float* un = W_hh + (size_t)(j + 2 * H_) * H_;
  for (int i0 = 0; i0 < H_; i0 += 64) {
    __syncthreads();
#pragma unroll
    for (int e = 0; e < 16; ++e) {
      int idx = tid + e * 256;
      int r = idx >> 6, c = idx & 63;
      xt[r][c] = h_in[r * H_ + i0 + c];
    }
    __syncthreads();
#pragma unroll
    for (int c = 0; c < 64; ++c) {
      float x = xt[b][c];
      gr = fmaf(x, ur[i0 + c], gr);
      gz = fmaf(x, uz[i0 + c], gz);
      gn = fmaf(x, un[i0 + c], gn);
    }
  }

  float r = 1.f / (1.f + expf(-(ar + gr)));
  float z = 1.f / (1.f + expf(-(az + gz)));
  float nn = tanhf(an + r * gn);
  float hp = h_in[b * H_ + j];
  float hv = (1.f - z) * nn + z * hp;
  h_out[b * H_ + j] = hv;
  out_h[((size_t)b * L + t) * H_ + j] = hv;
}

// ---------------- launch ----------------

extern "C" void kernel_launch(void* const* d_in, const int* in_sizes, int n_in,
                              void* d_out, int out_size, void* d_ws, size_t ws_size,
                              hipStream_t stream) {
  const float* emb    = (const float*)d_in[0];
  const float* value  = (const float*)d_in[1];
  const float* vmask  = (const float*)d_in[2];
  const float* state  = (const float*)d_in[3];
  const float* Wq     = (const float*)d_in[4];
  const float* Wk     = (const float*)d_in[5];
  const float* b_attn = (const float*)d_in[6];
  const float* w_cov  = (const float*)d_in[7];
  const float* v_attn = (const float*)d_in[8];
  const float* W_ih   = (const float*)d_in[9];
  const float* W_hh   = (const float*)d_in[10];
  const float* b_ih   = (const float*)d_in[11];
  const float* b_hh   = (const float*)d_in[12];

  float* out = (float*)d_out;
  float* attn_out = out + (size_t)B * L * H_;

  __half* vk_h  = (__half*)d_ws;                       // B*N*H fp16
  __half* val_h = vk_h + (size_t)B * N_ * H_;          // B*N*H fp16
  float* hb     = (float*)(val_h + (size_t)B * N_ * H_); // 2*B*H
  float* cov    = hb + 2 * B * H_;                     // B*N
  float* ctx    = cov + B * N_;                        // B*H
  float* q      = ctx + B * H_;                        // B*H
  float* scores = q + B * H_;                          // B*N

  k_init<<<128, 256, 0, stream>>>(state, hb, cov);
  k_cvt<<<(B * N_ * H_) / 1024, 256, 0, stream>>>(value, val_h);
  k_vk<<<dim3(8, 8, B), 256, 0, stream>>>(value, Wk, b_attn, vk_h);

  for (int t = 0; t < L; ++t) {
    const float* hin = hb + (size_t)(t & 1) * B * H_;
    float* hout = hb + (size_t)((t + 1) & 1) * B * H_;
    k_q<<<128, 256, 0, stream>>>(hin, Wq, q);
    k_score<<<dim3(4, B), 256, 0, stream>>>(vk_h, q, w_cov, v_attn, cov, vmask,
                                            scores);
    k_ctx<<<dim3(4, B), 256, 0, stream>>>(scores, val_h, cov, ctx, attn_out, t);
    k_gru<<<128, 256, 0, stream>>>(emb, ctx, W_ih, W_hh, b_ih, b_hh,
                                   hin, hout, out, t);
  }
}

// Round 3
// 9143.354 us; speedup vs baseline: 3.4750x; 3.4750x over previous
//
#include <hip/hip_runtime.h>
#include <hip/hip_fp16.h>
#include <math.h>

#define B 64
#define L 128
#define N_ 512
#define E_ 512
#define H_ 512
#define G3 1536
#define NEG -1e9f

// ---------------- precompute kernels (once per call) ----------------

// h state + cov init. h stored column-major: h_t[jh*64 + b]
__global__ __launch_bounds__(256) void k_init(const float* __restrict__ state,
                                              float* __restrict__ h_t,
                                              float* __restrict__ cov) {
  int i = blockIdx.x * 256 + threadIdx.x;  // 0..32767
  int jh = i >> 6, b = i & 63;
  h_t[i] = state[b * H_ + jh];
  cov[i] = 0.f;
}

// fp32 -> fp16 copy of value (context path)
__global__ __launch_bounds__(256) void k_cvt(const float* __restrict__ v,
                                             __half* __restrict__ o) {
  size_t i = ((size_t)blockIdx.x * 256 + threadIdx.x) * 4;
  float4 f = *(const float4*)(v + i);
  __half2* d = (__half2*)(o + i);
  d[0] = __floats2half2_rn(f.x, f.y);
  d[1] = __floats2half2_rn(f.z, f.w);
}

// vk[b,n,k] = sum_h value[b,n,h] * Wk[k,h] + b_attn[k]   (stored fp16)
__global__ __launch_bounds__(256) void k_vk(const float* __restrict__ value,
                                            const float* __restrict__ Wk,
                                            const float* __restrict__ b_attn,
                                            __half* __restrict__ vk) {
  int k0 = blockIdx.x * 64, n0 = blockIdx.y * 64, b = blockIdx.z;
  int tid = threadIdx.x;
  int tn = tid >> 4, tk = tid & 15;
  __shared__ float Vs[64][33];
  __shared__ float Ws[64][33];
  const float* vb = value + (size_t)b * N_ * H_;
  float acc[4][4] = {};
  for (int h0 = 0; h0 < H_; h0 += 32) {
#pragma unroll
    for (int e = 0; e < 8; ++e) {
      int idx = tid + e * 256;
      int r = idx >> 5, c = idx & 31;
      Vs[r][c] = vb[(size_t)(n0 + r) * H_ + h0 + c];
      Ws[r][c] = Wk[(size_t)(k0 + r) * H_ + h0 + c];
    }
    __syncthreads();
#pragma unroll
    for (int c = 0; c < 32; ++c) {
      float av[4], wv[4];
#pragma unroll
      for (int i = 0; i < 4; ++i) av[i] = Vs[tn * 4 + i][c];
#pragma unroll
      for (int jq = 0; jq < 4; ++jq) wv[jq] = Ws[tk * 4 + jq][c];
#pragma unroll
      for (int i = 0; i < 4; ++i)
#pragma unroll
        for (int jq = 0; jq < 4; ++jq) acc[i][jq] += av[i] * wv[jq];
    }
    __syncthreads();
  }
  __half* vkb = vk + (size_t)b * N_ * H_;
  float4 bav = *(const float4*)(b_attn + k0 + tk * 4);
#pragma unroll
  for (int i = 0; i < 4; ++i) {
    __half2 lo = __floats2half2_rn(acc[i][0] + bav.x, acc[i][1] + bav.y);
    __half2 hi = __floats2half2_rn(acc[i][2] + bav.z, acc[i][3] + bav.w);
    __half2* dst = (__half2*)&vkb[(size_t)(n0 + tn * 4 + i) * H_ + k0 + tk * 4];
    dst[0] = lo;
    dst[1] = hi;
  }
}

// gi_e[t, col, b] = emb[b,t,:] @ W_ih[col, :E] + b_ih[col]  (fp16, b fastest)
// grid (24 col-tiles, 128 t). Tile = 64 batches x 64 cols at fixed t.
__global__ __launch_bounds__(256) void k_gie(const float* __restrict__ emb,
                                             const float* __restrict__ W_ih,
                                             const float* __restrict__ b_ih,
                                             __half* __restrict__ gie) {
  int c0 = blockIdx.x * 64;
  int t = blockIdx.y;
  int tid = threadIdx.x;
  int tn = tid >> 4, tk = tid & 15;  // tn: 4 batches, tk: 4 cols
  __shared__ float As[64][33];
  __shared__ float Ws[64][33];
  float acc[4][4] = {};
  for (int h0 = 0; h0 < E_; h0 += 32) {
#pragma unroll
    for (int e = 0; e < 8; ++e) {
      int idx = tid + e * 256;
      int r = idx >> 5, c = idx & 31;
      As[r][c] = emb[((size_t)r * L + t) * E_ + h0 + c];
      Ws[r][c] = W_ih[(size_t)(c0 + r) * (E_ + H_) + h0 + c];
    }
    __syncthreads();
#pragma unroll
    for (int c = 0; c < 32; ++c) {
      float av[4], wv[4];
#pragma unroll
      for (int i = 0; i < 4; ++i) av[i] = As[tn * 4 + i][c];
#pragma unroll
      for (int jq = 0; jq < 4; ++jq) wv[jq] = Ws[tk * 4 + jq][c];
#pragma unroll
      for (int i = 0; i < 4; ++i)
#pragma unroll
        for (int jq = 0; jq < 4; ++jq) acc[i][jq] += av[i] * wv[jq];
    }
    __syncthreads();
  }
#pragma unroll
  for (int jq = 0; jq < 4; ++jq) {
    int col = c0 + tk * 4 + jq;
    float bi = b_ih[col];
    __half2 lo = __floats2half2_rn(acc[0][jq] + bi, acc[1][jq] + bi);
    __half2 hi = __floats2half2_rn(acc[2][jq] + bi, acc[3][jq] + bi);
    __half2* dst = (__half2*)(gie + ((size_t)t * G3 + col) * 64 + tn * 4);
    dst[0] = lo;
    dst[1] = hi;
  }
}

// ---------------- per-step K1: [q | gh] = h @ [Wq; Whh].T ----------------
// out1[j*64 + b], j<512: q (no bias); j>=512: gh = h@W_hh[j-512] + b_hh.
// grid 128 WGs x 512 thr; wave owns 2 cols, full K; h tile LDS conflict-free.
__global__ __launch_bounds__(512) void k1(const float* __restrict__ h_t,
                                          const float* __restrict__ Wq,
                                          const float* __restrict__ Whh,
                                          const float* __restrict__ b_hh,
                                          float* __restrict__ out1) {
  int tid = threadIdx.x;
  int b = tid & 63;
  int u = __builtin_amdgcn_readfirstlane(tid >> 6);  // 0..7
  int j = blockIdx.x * 16 + u * 2;
  const float* w0 = (j < 512) ? (Wq + (size_t)j * 512) : (Whh + (size_t)(j - 512) * 512);
  const float* w1 = (j + 1 < 512) ? (Wq + (size_t)(j + 1) * 512)
                                  : (Whh + (size_t)(j + 1 - 512) * 512);
  __shared__ float hs[64][64];
  float a0 = 0.f, a1 = 0.f;
  for (int k0 = 0; k0 < H_; k0 += 64) {
    __syncthreads();
#pragma unroll
    for (int e = 0; e < 8; ++e) {
      int idx = tid + e * 512;
      int r = idx >> 6, c = idx & 63;
      hs[r][c] = h_t[(size_t)(k0 + r) * 64 + c];
    }
    __syncthreads();
#pragma unroll
    for (int k4 = 0; k4 < 16; ++k4) {
      float4 w0v = *(const float4*)(w0 + k0 + k4 * 4);
      float4 w1v = *(const float4*)(w1 + k0 + k4 * 4);
      float h0v = hs[k4 * 4 + 0][b], h1v = hs[k4 * 4 + 1][b];
      float h2v = hs[k4 * 4 + 2][b], h3v = hs[k4 * 4 + 3][b];
      a0 = fmaf(h0v, w0v.x, a0); a0 = fmaf(h1v, w0v.y, a0);
      a0 = fmaf(h2v, w0v.z, a0); a0 = fmaf(h3v, w0v.w, a0);
      a1 = fmaf(h0v, w1v.x, a1); a1 = fmaf(h1v, w1v.y, a1);
      a1 = fmaf(h2v, w1v.z, a1); a1 = fmaf(h3v, w1v.w, a1);
    }
  }
  if (j >= 512) a0 += b_hh[j - 512];
  if (j + 1 >= 512) a1 += b_hh[j + 1 - 512];
  out1[(size_t)j * 64 + b] = a0;
  out1[(size_t)(j + 1) * 64 + b] = a1;
}

// ---------------- per-step K2: fused attention, one WG per batch ----------
__global__ __launch_bounds__(1024) void k2(
    const __half* __restrict__ vk, const __half* __restrict__ val_h,
    const float* __restrict__ out1, const float* __restrict__ w_cov,
    const float* __restrict__ v_attn, const float* __restrict__ vmask,
    float* __restrict__ cov, float* __restrict__ ctx_t,
    float* __restrict__ attn_out, int t) {
  int b = blockIdx.x;
  int tid = threadIdx.x;
  int w = tid >> 6, l = tid & 63;
  __shared__ float qs[H_];
  __shared__ float covs[N_];
  __shared__ float sc[N_];
  __shared__ float red[512];
  __shared__ float at[N_];
  __shared__ float cpart[4][256][2];

  if (tid < 512) {
    qs[tid] = out1[(size_t)tid * 64 + b];
    covs[tid] = cov[b * N_ + tid];
  }
  __syncthreads();

  float q8[8], wc8[8], va8[8];
  {
    float4 a0 = *(const float4*)(w_cov + l * 8);
    float4 a1 = *(const float4*)(w_cov + l * 8 + 4);
    wc8[0] = a0.x; wc8[1] = a0.y; wc8[2] = a0.z; wc8[3] = a0.w;
    wc8[4] = a1.x; wc8[5] = a1.y; wc8[6] = a1.z; wc8[7] = a1.w;
    float4 b0 = *(const float4*)(v_attn + l * 8);
    float4 b1 = *(const float4*)(v_attn + l * 8 + 4);
    va8[0] = b0.x; va8[1] = b0.y; va8[2] = b0.z; va8[3] = b0.w;
    va8[4] = b1.x; va8[5] = b1.y; va8[6] = b1.z; va8[7] = b1.w;
  }
#pragma unroll
  for (int kk = 0; kk < 8; ++kk) q8[kk] = qs[l * 8 + kk];

  const __half* vkb = vk + (size_t)b * N_ * H_;
  for (int r = 0; r < 32; ++r) {
    int n = w * 32 + r;
    float cv = covs[n];
    float4 raw = *(const float4*)(vkb + (size_t)n * H_ + l * 8);
    const __half2* h2p = (const __half2*)&raw;
    float p = 0.f;
#pragma unroll
    for (int kk = 0; kk < 4; ++kk) {
      float2 f = __half22float2(h2p[kk]);
      float e0 = fmaf(cv, wc8[2 * kk], q8[2 * kk]) + f.x;
      float e1 = fmaf(cv, wc8[2 * kk + 1], q8[2 * kk + 1]) + f.y;
      p = fmaf(fmaxf(e0, 0.f), va8[2 * kk], p);
      p = fmaf(fmaxf(e1, 0.f), va8[2 * kk + 1], p);
    }
#pragma unroll
    for (int off = 32; off; off >>= 1) p += __shfl_xor(p, off);
    if (l == 0) sc[n] = p;
  }
  __syncthreads();

  float sv = 0.f;
  if (tid < 512) {
    sv = (vmask[b * N_ + tid] > 0.f) ? sc[tid] : NEG;
    red[tid] = sv;
  }
  __syncthreads();
#pragma unroll
  for (int s = 256; s; s >>= 1) {
    if (tid < s) red[tid] = fmaxf(red[tid], red[tid + s]);
    __syncthreads();
  }
  float m = red[0];
  __syncthreads();
  float p = 0.f;
  if (tid < 512) {
    p = expf(sv - m);
    red[tid] = p;
  }
  __syncthreads();
#pragma unroll
  for (int s = 256; s; s >>= 1) {
    if (tid < s) red[tid] += red[tid + s];
    __syncthreads();
  }
  float rs = 1.f / red[0];
  if (tid < 512) {
    float a = p * rs;
    at[tid] = a;
    cov[b * N_ + tid] = covs[tid] + a;
    attn_out[((size_t)b * L + t) * N_ + tid] = a;
  }
  __syncthreads();

  // context: 4 n-quarters x 256 half2-columns
  int part = tid >> 8, h2i = tid & 255;
  const __half2* vb = (const __half2*)(val_h + (size_t)b * N_ * H_) + h2i;
  float cx = 0.f, cy = 0.f;
  for (int n = part * 128; n < part * 128 + 128; ++n) {
    float a = at[n];
    float2 f = __half22float2(vb[(size_t)n * (H_ / 2)]);
    cx = fmaf(a, f.x, cx);
    cy = fmaf(a, f.y, cy);
  }
  cpart[part][h2i][0] = cx;
  cpart[part][h2i][1] = cy;
  __syncthreads();
  if (tid < 256) {
    float sx = cpart[0][tid][0] + cpart[1][tid][0] + cpart[2][tid][0] + cpart[3][tid][0];
    float sy = cpart[0][tid][1] + cpart[1][tid][1] + cpart[2][tid][1] + cpart[3][tid][1];
    ctx_t[(size_t)(2 * tid) * 64 + b] = sx;
    ctx_t[(size_t)(2 * tid + 1) * 64 + b] = sy;
  }
}

// ---------------- per-step K3: gc = ctx @ W_ih[:,E:].T + GRU pointwise -----
// grid 128 WGs x 512 thr; wave (u,kh): triple u of this WG's 4 jh, k-half kh.
__global__ __launch_bounds__(512) void k3(
    const float* __restrict__ ctx_t, const float* __restrict__ W_ih,
    const __half* __restrict__ gie, const float* __restrict__ out1,
    const float* __restrict__ h_in, float* __restrict__ h_out,
    float* __restrict__ out_h, int t) {
  int tid = threadIdx.x;
  int b = tid & 63;
  int wv = __builtin_amdgcn_readfirstlane(tid >> 6);  // 0..7
  int u = wv & 3;
  int kh = wv >> 2;
  int jh = blockIdx.x * 4 + u;
  const float* wr = W_ih + (size_t)jh * (E_ + H_) + E_;
  const float* wz = W_ih + (size_t)(512 + jh) * (E_ + H_) + E_;
  const float* wn = W_ih + (size_t)(1024 + jh) * (E_ + H_) + E_;
  __shared__ float cs[2][64][64];
  __shared__ float comb[4][3][64];
  float ar = 0.f, az = 0.f, an = 0.f;
  for (int i = 0; i < 4; ++i) {
    __syncthreads();
#pragma unroll
    for (int e = 0; e < 8; ++e) {
      int idx = tid + e * 512;
      int r = idx >> 6, c = idx & 63;
      cs[0][r][c] = ctx_t[(size_t)(i * 64 + r) * 64 + c];
      cs[1][r][c] = ctx_t[(size_t)((i + 4) * 64 + r) * 64 + c];
    }
    __syncthreads();
    int ko = kh * 256 + i * 64;
#pragma unroll
    for (int k4 = 0; k4 < 16; ++k4) {
      float4 wvr = *(const float4*)(wr + ko + k4 * 4);
      float4 wvz = *(const float4*)(wz + ko + k4 * 4);
      float4 wvn = *(const float4*)(wn + ko + k4 * 4);
      float c0 = cs[kh][k4 * 4 + 0][b], c1 = cs[kh][k4 * 4 + 1][b];
      float c2 = cs[kh][k4 * 4 + 2][b], c3 = cs[kh][k4 * 4 + 3][b];
      ar = fmaf(c0, wvr.x, ar); ar = fmaf(c1, wvr.y, ar);
      ar = fmaf(c2, wvr.z, ar); ar = fmaf(c3, wvr.w, ar);
      az = fmaf(c0, wvz.x, az); az = fmaf(c1, wvz.y, az);
      az = fmaf(c2, wvz.z, az); az = fmaf(c3, wvz.w, az);
      an = fmaf(c0, wvn.x, an); an = fmaf(c1, wvn.y, an);
      an = fmaf(c2, wvn.z, an); an = fmaf(c3, wvn.w, an);
    }
  }
  if (kh == 1) {
    comb[u][0][b] = ar;
    comb[u][1][b] = az;
    comb[u][2][b] = an;
  }
  __syncthreads();
  if (kh == 0) {
    ar += comb[u][0][b];
    az += comb[u][1][b];
    an += comb[u][2][b];
    const __half* g = gie + (size_t)t * G3 * 64;
    float gir = __half2float(g[(size_t)jh * 64 + b]);
    float giz = __half2float(g[(size_t)(512 + jh) * 64 + b]);
    float gin = __half2float(g[(size_t)(1024 + jh) * 64 + b]);
    float ghr = out1[(size_t)(512 + jh) * 64 + b];
    float ghz = out1[(size_t)(1024 + jh) * 64 + b];
    float ghn = out1[(size_t)(1536 + jh) * 64 + b];
    float r = 1.f / (1.f + expf(-(gir + ar + ghr)));
    float z = 1.f / (1.f + expf(-(giz + az + ghz)));
    float nn = tanhf(gin + an + r * ghn);
    float hp = h_in[(size_t)jh * 64 + b];
    float hv = (1.f - z) * nn + z * hp;
    h_out[(size_t)jh * 64 + b] = hv;
    out_h[((size_t)b * L + t) * H_ + jh] = hv;
  }
}

// ---------------- launch ----------------

extern "C" void kernel_launch(void* const* d_in, const int* in_sizes, int n_in,
                              void* d_out, int out_size, void* d_ws, size_t ws_size,
                              hipStream_t stream) {
  const float* emb    = (const float*)d_in[0];
  const float* value  = (const float*)d_in[1];
  const float* vmask  = (const float*)d_in[2];
  const float* state  = (const float*)d_in[3];
  const float* Wq     = (const float*)d_in[4];
  const float* Wk     = (const float*)d_in[5];
  const float* b_attn = (const float*)d_in[6];
  const float* w_cov  = (const float*)d_in[7];
  const float* v_attn = (const float*)d_in[8];
  const float* W_ih   = (const float*)d_in[9];
  const float* W_hh   = (const float*)d_in[10];
  const float* b_ih   = (const float*)d_in[11];
  const float* b_hh   = (const float*)d_in[12];

  float* out = (float*)d_out;
  float* attn_out = out + (size_t)B * L * H_;

  __half* vk_h  = (__half*)d_ws;                         // B*N*H fp16
  __half* val_h = vk_h + (size_t)B * N_ * H_;            // B*N*H fp16
  __half* gie_h = val_h + (size_t)B * N_ * H_;           // L*G3*B fp16
  float* hb     = (float*)(gie_h + (size_t)L * G3 * B);  // 2*H*B
  float* cov    = hb + (size_t)2 * H_ * B;               // B*N
  float* ctx_t  = cov + (size_t)B * N_;                  // H*B
  float* out1   = ctx_t + (size_t)H_ * B;                // 2048*B

  k_init<<<128, 256, 0, stream>>>(state, hb, cov);
  k_cvt<<<(B * N_ * H_) / 1024, 256, 0, stream>>>(value, val_h);
  k_vk<<<dim3(8, 8, B), 256, 0, stream>>>(value, Wk, b_attn, vk_h);
  k_gie<<<dim3(24, 128), 256, 0, stream>>>(emb, W_ih, b_ih, gie_h);

  for (int t = 0; t < L; ++t) {
    const float* hin = hb + (size_t)(t & 1) * H_ * B;
    float* hout = hb + (size_t)((t + 1) & 1) * H_ * B;
    k1<<<128, 512, 0, stream>>>(hin, Wq, W_hh, b_hh, out1);
    k2<<<64, 1024, 0, stream>>>(vk_h, val_h, out1, w_cov, v_attn, vmask, cov,
                                ctx_t, attn_out, t);
    k3<<<128, 512, 0, stream>>>(ctx_t, W_ih, gie_h, out1, hin, hout, out, t);
  }
}